// Round 11
// baseline (218.765 us; speedup 1.0000x reference)
//
#include <hip/hip_runtime.h>
#include <hip/hip_fp16.h>

#define HD 16

static constexpr int NN = 100000;   // nodes
static constexpr int EE = 3200000;  // edges (before self-loops)
static constexpr int GG = 1000;     // graphs
static constexpr int ET = EE + NN;  // edges incl. self-loops
static constexpr float NEG = 0.2f;  // leaky_relu slope
static constexpr float LOG2E = 1.44269504f;

static constexpr int BSH = 8;                       // 256 nodes per bucket
static constexpr int NB = (NN + 255) >> BSH;        // 391 buckets
static constexpr int EPB = 8192;                    // edges per block (bucket passes)
static constexpr int GB = (ET + EPB - 1) / EPB;     // 403 blocks
static constexpr int ITER = EPB / 1024;             // 8 edges per thread

__device__ __forceinline__ int imin(int a, int b) { return a < b ? a : b; }

// unpack 2 fp16 from a dword
__device__ __forceinline__ float2 up2(unsigned u) {
  __half2 h = *reinterpret_cast<__half2*>(&u);
  return __half22float2(h);
}

// ---- DPP helpers ----
template <int N>
__device__ __forceinline__ float row_ror_add(float v) {
  int m = __builtin_amdgcn_update_dpp(0, __float_as_int(v), 0x120 + N, 0xF, 0xF, true);
  return v + __int_as_float(m);
}
// pair sum (lanes differing in bit0) via quad_perm [1,0,3,2]
__device__ __forceinline__ float pair_sum(float v) {
  int m = __builtin_amdgcn_update_dpp(0, __float_as_int(v), 0xB1, 0xF, 0xF, true);
  return v + __int_as_float(m);
}
// reduce over the 16 edge-slots of a 32-lane half (parity-preserving rotations
// within each 16-row, then cross-row); every lane ends with its octet's total
__device__ __forceinline__ float slot_red(float v) {
  v = row_ror_add<2>(v);
  v = row_ror_add<4>(v);
  v = row_ror_add<8>(v);
  v += __shfl_xor(v, 16, 64);
  return v;
}

// ---------- pass A: coarse histogram (LDS-aggregated) ----------
__global__ void k_chist(const int* __restrict__ edst, int* __restrict__ chist) {
  __shared__ int sh[NB];
  int t = threadIdx.x;
  for (int i = t; i < NB; i += 1024) sh[i] = 0;
  __syncthreads();
  int b0 = blockIdx.x * EPB;
#pragma unroll
  for (int i = 0; i < ITER; ++i) {
    int e = b0 + t + i * 1024;
    if (e < ET) {
      int d = (e < EE) ? edst[e] : e - EE;  // self-loop block appended at end
      atomicAdd(&sh[d >> BSH], 1);
    }
  }
  __syncthreads();
  for (int i = t; i < NB; i += 1024)
    if (sh[i]) atomicAdd(&chist[i], sh[i]);
}

// ---------- scan coarse histogram -> bucket bases ----------
__global__ void k_cscan(const int* __restrict__ chist, int* __restrict__ cbase,
                        int* __restrict__ ccur, int* __restrict__ rowptr) {
  __shared__ int sh[512];
  int t = threadIdx.x;
  sh[t] = (t < NB) ? chist[t] : 0;
  __syncthreads();
  for (int off = 1; off < 512; off <<= 1) {
    int v = sh[t];
    int a = (t >= off) ? sh[t - off] : 0;
    __syncthreads();
    sh[t] = v + a;
    __syncthreads();
  }
  if (t < NB) {
    int b = (t == 0) ? 0 : sh[t - 1];
    cbase[t] = b;
    ccur[t] = b;
  }
  if (t == 0) rowptr[NN] = ET;
}

// ---------- pass B: scatter packed records into coarse bucket regions ----------
// record = (dst & 255) << 17 | src   (src < 2^17, local dst < 2^8 -> 25 bits)
__global__ void k_csplit(const int* __restrict__ esrc, const int* __restrict__ edst,
                         int* __restrict__ ccur, unsigned* __restrict__ tmp) {
  __shared__ int hist[NB];
  __shared__ int base[NB];
  int t = threadIdx.x;
  for (int i = t; i < NB; i += 1024) hist[i] = 0;
  __syncthreads();
  int b0 = blockIdx.x * EPB;
  int sl[ITER], dl[ITER];
#pragma unroll
  for (int i = 0; i < ITER; ++i) {
    int e = b0 + t + i * 1024;
    int s = -1, d = 0;
    if (e < ET) {
      if (e < EE) { s = esrc[e]; d = edst[e]; } else { s = e - EE; d = s; }
      atomicAdd(&hist[d >> BSH], 1);
    }
    sl[i] = s; dl[i] = d;
  }
  __syncthreads();
  for (int i = t; i < NB; i += 1024) {
    int c = hist[i];
    base[i] = c ? atomicAdd(&ccur[i], c) : 0;  // one reservation per bucket per block
    hist[i] = 0;                               // reuse as running counter
  }
  __syncthreads();
#pragma unroll
  for (int i = 0; i < ITER; ++i) {
    int s = sl[i];
    if (s >= 0) {
      int d = dl[i], bb = d >> BSH;
      int slot = base[bb] + atomicAdd(&hist[bb], 1);
      tmp[slot] = ((unsigned)(d & 255) << 17) | (unsigned)s;
    }
  }
}

// ---------- pass C: per-bucket fine counting sort -> rowptr + psrc ----------
__global__ void k_fsort(const unsigned* __restrict__ tmp, const int* __restrict__ cbase,
                        const int* __restrict__ chist, int* __restrict__ rowptr,
                        int* __restrict__ psrc) {
  __shared__ int fh[256];
  __shared__ int fs[256];
  int b = blockIdx.x, t = threadIdx.x;
  if (t < 256) fh[t] = 0;
  __syncthreads();
  int beg = cbase[b], cnt = chist[b];
  for (int i = t; i < cnt; i += 1024)
    atomicAdd(&fh[tmp[beg + i] >> 17], 1);
  __syncthreads();
  if (t < 256) fs[t] = fh[t];
  __syncthreads();
  for (int off = 1; off < 256; off <<= 1) {
    int v = 0, a = 0;
    if (t < 256) { v = fs[t]; if (t >= off) a = fs[t - off]; }
    __syncthreads();
    if (t < 256) fs[t] = v + a;
    __syncthreads();
  }
  if (t < 256) {
    int ex = fs[t] - fh[t];  // exclusive within bucket
    fs[t] = ex;              // becomes the running placement counter
    int node = (b << BSH) + t;
    if (node < NN) rowptr[node] = beg + ex;
  }
  __syncthreads();
  for (int i = t; i < cnt; i += 1024) {
    unsigned v = tmp[beg + i];
    int ld = v >> 17;
    psrc[beg + atomicAdd(&fs[ld], 1)] = (int)(v & 0x1FFFFu);
  }
}

// ---------- fold inter-layer linear into next projections: Wc = W@P, bc = b@P + bp ----------
__global__ void k_comb(const float* __restrict__ W0, const float* __restrict__ b0,
                       const float* __restrict__ Wl1, const float* __restrict__ bl1,
                       const float* __restrict__ Wr1, const float* __restrict__ br1,
                       const float* __restrict__ W1, const float* __restrict__ b1,
                       const float* __restrict__ Wl2, const float* __restrict__ bl2,
                       const float* __restrict__ Wr2, const float* __restrict__ br2,
                       float* __restrict__ Wc0l, float* __restrict__ bc0l,
                       float* __restrict__ Wc0r, float* __restrict__ bc0r,
                       float* __restrict__ Wc1l, float* __restrict__ bc1l,
                       float* __restrict__ Wc1r, float* __restrict__ bc1r) {
  const float *W, *b, *P, *bp;
  float *Wo, *bo;
  switch (blockIdx.x) {
    case 0:  W = W0; b = b0; P = Wl1; bp = bl1; Wo = Wc0l; bo = bc0l; break;
    case 1:  W = W0; b = b0; P = Wr1; bp = br1; Wo = Wc0r; bo = bc0r; break;
    case 2:  W = W1; b = b1; P = Wl2; bp = bl2; Wo = Wc1l; bo = bc1l; break;
    default: W = W1; b = b1; P = Wr2; bp = br2; Wo = Wc1r; bo = bc1r; break;
  }
  int t = threadIdx.x;  // 256
  int c = t >> 4, k = t & 15;
  float s = 0.f;
#pragma unroll
  for (int i = 0; i < 16; ++i) s = fmaf(W[c * 16 + i], P[i * 16 + k], s);
  Wo[t] = s;
  if (t < 16) {
    float sb = bp[t];
#pragma unroll
    for (int i = 0; i < 16; ++i) sb = fmaf(b[i], P[i * 16 + t], sb);
    bo[t] = sb;
  }
}

// ---------- fused conv layer: TWO nodes per wave, PAIR layout ----------
// Half = 32 lanes = 16 edge-slots x 2 feature-octets. Each lane loads 16B
// (8 fp16 features) of one edge -> ONE gather instruction covers 32 edges per
// wave (2x round-10) and per-edge lane-address count halves. In-loop cross-lane
// work is a single DPP pair-swap; slot reduce is post-loop (parity-preserving
// DPP rotations + one shfl). Per-lane loop bound doubles as validity (DPP only
// spans same-slot lanes, which share the trip count).
// MODE 0 = first (xl/xr rank-1 from x), 1 = mid, 2 = last (pool).
template <int MODE>
__global__ void k_conv(const int* __restrict__ rowptr, const int* __restrict__ psrc,
                       const float* __restrict__ x,
                       const float* __restrict__ Wl0, const float* __restrict__ bl0,
                       const float* __restrict__ Wr0, const float* __restrict__ br0,
                       const __half* __restrict__ xlh, const float* __restrict__ xr,
                       const float* __restrict__ att, const float* __restrict__ cbias,
                       const float* __restrict__ Wcl, const float* __restrict__ bcl,
                       const float* __restrict__ Wcr, const float* __restrict__ bcr,
                       const float* __restrict__ Wlast, const float* __restrict__ blast,
                       __half* __restrict__ oxlh, float* __restrict__ oxr,
                       float* __restrict__ gpool, const int* __restrict__ batch) {
  __shared__ float hsh[4][2][16];
  int gt = blockIdx.x * blockDim.x + threadIdx.x;
  int wave = gt >> 6;
  int lane = threadIdx.x & 63;
  int hf = lane >> 5;        // which node of the pair
  int lane5 = lane & 31;
  int slot = lane5 >> 1;     // edge slot 0..15
  int o = lane & 1;          // feature octet (features 8o..8o+7)
  int n = wave * 2 + hf;
  if (n >= NN) return;
  int f0 = o * 8;
  // per-lane octet of att (x LOG2E), xr, and (MODE 0) Wl0/bl0
  float4 attA = *reinterpret_cast<const float4*>(att + f0);
  float4 attB = *reinterpret_cast<const float4*>(att + f0 + 4);
  attA.x *= LOG2E; attA.y *= LOG2E; attA.z *= LOG2E; attA.w *= LOG2E;
  attB.x *= LOG2E; attB.y *= LOG2E; attB.z *= LOG2E; attB.w *= LOG2E;
  float4 xrA, xrB, wlA, wlB, blA, blB;
  if constexpr (MODE == 0) {
    wlA = *reinterpret_cast<const float4*>(Wl0 + f0);
    wlB = *reinterpret_cast<const float4*>(Wl0 + f0 + 4);
    blA = *reinterpret_cast<const float4*>(bl0 + f0);
    blB = *reinterpret_cast<const float4*>(bl0 + f0 + 4);
    float4 wrA = *reinterpret_cast<const float4*>(Wr0 + f0);
    float4 wrB = *reinterpret_cast<const float4*>(Wr0 + f0 + 4);
    float4 brA = *reinterpret_cast<const float4*>(br0 + f0);
    float4 brB = *reinterpret_cast<const float4*>(br0 + f0 + 4);
    float xn = x[n];
    xrA.x = fmaf(xn, wrA.x, brA.x); xrA.y = fmaf(xn, wrA.y, brA.y);
    xrA.z = fmaf(xn, wrA.z, brA.z); xrA.w = fmaf(xn, wrA.w, brA.w);
    xrB.x = fmaf(xn, wrB.x, brB.x); xrB.y = fmaf(xn, wrB.y, brB.y);
    xrB.z = fmaf(xn, wrB.z, brB.z); xrB.w = fmaf(xn, wrB.w, brB.w);
  } else {
    xrA = *reinterpret_cast<const float4*>(xr + (size_t)n * HD + f0);
    xrB = *reinterpret_cast<const float4*>(xr + (size_t)n * HD + f0 + 4);
  }
  int beg = rowptr[n], end = rowptr[n + 1];
  int e1 = end - 1;
  int p = beg + slot;
  // pipeline prologue: iter-0 value + iter-1 index
  int i0 = psrc[imin(p, e1)];
  uint4 cv;           // MODE!=0: 8 fp16 features of current edge
  float cx;           // MODE==0: raw x of current edge's src
  if constexpr (MODE == 0) {
    cx = x[i0];
  } else {
    cv = *reinterpret_cast<const uint4*>(
        (const char*)xlh + (size_t)i0 * 32 + (size_t)o * 16);
  }
  int t0 = psrc[imin(p + 16, e1)];
  float l = 0.f;
  float a0 = 0.f, a1 = 0.f, a2 = 0.f, a3 = 0.f;
  float a4 = 0.f, a5 = 0.f, a6 = 0.f, a7 = 0.f;
  for (; p < end; p += 16) {
    // issue next iteration's value gather + index prefetch
    uint4 nv;
    float nx;
    if constexpr (MODE == 0) {
      nx = x[t0];
    } else {
      nv = *reinterpret_cast<const uint4*>(
          (const char*)xlh + (size_t)t0 * 32 + (size_t)o * 16);
    }
    int t1 = psrc[imin(p + 32, e1)];
    // materialize current edge's 8 features
    float x0, x1, x2, x3, x4, x5, x6, x7;
    if constexpr (MODE == 0) {
      x0 = fmaf(cx, wlA.x, blA.x); x1 = fmaf(cx, wlA.y, blA.y);
      x2 = fmaf(cx, wlA.z, blA.z); x3 = fmaf(cx, wlA.w, blA.w);
      x4 = fmaf(cx, wlB.x, blB.x); x5 = fmaf(cx, wlB.y, blB.y);
      x6 = fmaf(cx, wlB.z, blB.z); x7 = fmaf(cx, wlB.w, blB.w);
    } else {
      float2 f01 = up2(cv.x), f23 = up2(cv.y), f45 = up2(cv.z), f67 = up2(cv.w);
      x0 = f01.x; x1 = f01.y; x2 = f23.x; x3 = f23.y;
      x4 = f45.x; x5 = f45.y; x6 = f67.x; x7 = f67.y;
    }
    // 8-feature score partial
    float u, sp = 0.f;
    u = x0 + xrA.x; u = fmaxf(u, NEG * u); sp = fmaf(u, attA.x, sp);
    u = x1 + xrA.y; u = fmaxf(u, NEG * u); sp = fmaf(u, attA.y, sp);
    u = x2 + xrA.z; u = fmaxf(u, NEG * u); sp = fmaf(u, attA.z, sp);
    u = x3 + xrA.w; u = fmaxf(u, NEG * u); sp = fmaf(u, attA.w, sp);
    u = x4 + xrB.x; u = fmaxf(u, NEG * u); sp = fmaf(u, attB.x, sp);
    u = x5 + xrB.y; u = fmaxf(u, NEG * u); sp = fmaf(u, attB.y, sp);
    u = x6 + xrB.z; u = fmaxf(u, NEG * u); sp = fmaf(u, attB.z, sp);
    u = x7 + xrB.w; u = fmaxf(u, NEG * u); sp = fmaf(u, attB.w, sp);
    float sc = pair_sum(sp);          // full 16-feature score (both octets)
    float pe = __builtin_amdgcn_exp2f(sc);
    l += pe;
    a0 = fmaf(pe, x0, a0); a1 = fmaf(pe, x1, a1);
    a2 = fmaf(pe, x2, a2); a3 = fmaf(pe, x3, a3);
    a4 = fmaf(pe, x4, a4); a5 = fmaf(pe, x5, a5);
    a6 = fmaf(pe, x6, a6); a7 = fmaf(pe, x7, a7);
    // rotate pipeline
    if constexpr (MODE == 0) cx = nx; else cv = nv;
    t0 = t1;
  }
  // reduce over the 16 slots of the half (lanes that never looped contribute 0)
  l = slot_red(l);
  a0 = slot_red(a0); a1 = slot_red(a1); a2 = slot_red(a2); a3 = slot_red(a3);
  a4 = slot_red(a4); a5 = slot_red(a5); a6 = slot_red(a6); a7 = slot_red(a7);
  float rl = __builtin_amdgcn_rcpf(l);
  float4 cbA = *reinterpret_cast<const float4*>(cbias + f0);
  float4 cbB = *reinterpret_cast<const float4*>(cbias + f0 + 4);
  float h0 = fmaxf(fmaf(a0, rl, cbA.x), 0.f);
  float h1 = fmaxf(fmaf(a1, rl, cbA.y), 0.f);
  float h2 = fmaxf(fmaf(a2, rl, cbA.z), 0.f);
  float h3 = fmaxf(fmaf(a3, rl, cbA.w), 0.f);
  float h4 = fmaxf(fmaf(a4, rl, cbB.x), 0.f);
  float h5 = fmaxf(fmaf(a5, rl, cbB.y), 0.f);
  float h6 = fmaxf(fmaf(a6, rl, cbB.z), 0.f);
  float h7 = fmaxf(fmaf(a7, rl, cbB.w), 0.f);
  // publish h to LDS: slot-0 lanes (lane5 = 0,1) hold the full sums, each
  // writes its octet
  int w = threadIdx.x >> 6;
  if (lane5 < 2) {
    *reinterpret_cast<float4*>(&hsh[w][hf][f0]) = make_float4(h0, h1, h2, h3);
    *reinterpret_cast<float4*>(&hsh[w][hf][f0 + 4]) = make_float4(h4, h5, h6, h7);
  }
  int sub = lane5 >> 4;      // 0 or 1
  int k = lane5 & 15;
  const float* hrow = hsh[w][hf];
  if constexpr (MODE == 2) {
    // o = h @ Wlast (+ blast): sub-split rows, xor-16 combine
    float ov = 0.f;
#pragma unroll
    for (int i = 0; i < 8; ++i) {
      int c = 8 * sub + i;
      ov = fmaf(hrow[c], Wlast[c * HD + k], ov);
    }
    ov += __shfl_xor(ov, 16, 64);
    if (sub == 0) atomicAdd(gpool + (size_t)batch[n] * HD + k, ov + blast[k]);
  } else {
    // sub0 computes full xl2 (Wcl), sub1 computes full xr2 (Wcr) in parallel
    const float* Wsel = sub ? Wcr : Wcl;
    float ov = 0.f;
#pragma unroll
    for (int c = 0; c < 16; ++c) ov = fmaf(hrow[c], Wsel[c * HD + k], ov);
    if (sub == 0) oxlh[(size_t)n * HD + k] = __float2half(ov + bcl[k]);
    else          oxr[(size_t)n * HD + k] = ov + bcr[k];
  }
}

// ---------- graph-level MLP head: [G,16] -> [G,1] ----------
__global__ void k_mlp(const float* __restrict__ g,
                      const float* __restrict__ W0, const float* __restrict__ b0,
                      const float* __restrict__ W1, const float* __restrict__ b1,
                      const float* __restrict__ W2, const float* __restrict__ b2,
                      float* __restrict__ out) {
  int gi = blockIdx.x * blockDim.x + threadIdx.x;
  if (gi >= GG) return;
  float v[HD], a[HD];
  const float4* g4 = reinterpret_cast<const float4*>(g + (size_t)gi * HD);
#pragma unroll
  for (int i = 0; i < 4; ++i) {
    float4 tv = g4[i];
    v[4 * i] = tv.x; v[4 * i + 1] = tv.y; v[4 * i + 2] = tv.z; v[4 * i + 3] = tv.w;
  }
#pragma unroll
  for (int j = 0; j < HD; ++j) {
    float s = b0[j];
#pragma unroll
    for (int kk = 0; kk < HD; ++kk) s = fmaf(v[kk], W0[kk * HD + j], s);
    a[j] = s > 0.f ? s : 0.f;
  }
#pragma unroll
  for (int j = 0; j < HD; ++j) {
    float s = b1[j];
#pragma unroll
    for (int kk = 0; kk < HD; ++kk) s = fmaf(a[kk], W1[kk * HD + j], s);
    v[j] = s > 0.f ? s : 0.f;
  }
  float s = b2[0];
#pragma unroll
  for (int kk = 0; kk < HD; ++kk) s = fmaf(v[kk], W2[kk], s);
  out[gi] = s;
}

extern "C" void kernel_launch(void* const* d_in, const int* in_sizes, int n_in,
                              void* d_out, int out_size, void* d_ws, size_t ws_size,
                              hipStream_t stream) {
  const float* x = (const float*)d_in[0];
  const int* ei = (const int*)d_in[1];  // [2, EE] int32
  const int* batch = (const int*)d_in[2];
  const int* esrc = ei;
  const int* edst = ei + EE;

  const float* cW[3][6];  // Wl bl Wr br att bias
  const float* lW[3][2];  // W b
  int i = 3;
  for (int l = 0; l < 3; ++l) {
    for (int j = 0; j < 6; ++j) cW[l][j] = (const float*)d_in[i++];
    lW[l][0] = (const float*)d_in[i++];
    lW[l][1] = (const float*)d_in[i++];
  }
  const float *oW[3], *ob[3];
  for (int j = 0; j < 3; ++j) {
    oW[j] = (const float*)d_in[i++];
    ob[j] = (const float*)d_in[i++];
  }

  // workspace carve-up (~33 MB), 256B-aligned slices
  char* ws = (char*)d_ws;
  size_t off = 0;
  auto alloc = [&](size_t bytes) {
    void* p = ws + off;
    off = (off + bytes + 255) & ~(size_t)255;
    return p;
  };
  int* psrc = (int*)alloc((size_t)ET * 4);
  int* rowptr = (int*)alloc((size_t)(NN + 1) * 4);
  int* chist = (int*)alloc((size_t)NB * 4);
  int* cbase = (int*)alloc((size_t)NB * 4);
  int* ccur = (int*)alloc((size_t)NB * 4);
  float* Wc0l = (float*)alloc(256 * 4);
  float* Wc0r = (float*)alloc(256 * 4);
  float* Wc1l = (float*)alloc(256 * 4);
  float* Wc1r = (float*)alloc(256 * 4);
  float* bc0l = (float*)alloc(16 * 4);
  float* bc0r = (float*)alloc(16 * 4);
  float* bc1l = (float*)alloc(16 * 4);
  float* bc1r = (float*)alloc(16 * 4);
  // union region: tmp (ET*4 = 13.2MB) dead after k_fsort; feature buffers
  // (2x half 3.2MB + 2x f32 6.4MB + gbuf 64KB = 19.3MB) written only after.
  size_t NNHD = (size_t)NN * HD;
  size_t featBytes = NNHD * 12 + (size_t)GG * HD * 4;
  size_t uniBytes = (size_t)ET * 4 > featBytes ? (size_t)ET * 4 : featBytes;
  char* uni = (char*)alloc(uniBytes);
  unsigned* tmp = (unsigned*)uni;
  __half* xlhB = (__half*)uni;
  float* xrB = (float*)(uni + NNHD * 2);
  __half* xlhA = (__half*)(uni + NNHD * 6);
  float* xrA = (float*)(uni + NNHD * 8);
  float* gbuf = (float*)(uni + NNHD * 12);

  const int B = 256;
  const int gConv = (NN * 32 + B - 1) / B;  // HALF-wave per node (2 nodes/wave)
  const int gMlp = (GG + B - 1) / B;

  hipMemsetAsync(chist, 0, (size_t)NB * 4, stream);

  // tiny weight-fold kernel (independent of CSR; overlaps it)
  k_comb<<<4, 256, 0, stream>>>(lW[0][0], lW[0][1],
                                cW[1][0], cW[1][1], cW[1][2], cW[1][3],
                                lW[1][0], lW[1][1],
                                cW[2][0], cW[2][1], cW[2][2], cW[2][3],
                                Wc0l, bc0l, Wc0r, bc0r, Wc1l, bc1l, Wc1r, bc1r);

  // CSR build: all per-edge atomics in LDS
  k_chist<<<GB, 1024, 0, stream>>>(edst, chist);
  k_cscan<<<1, 512, 0, stream>>>(chist, cbase, ccur, rowptr);
  k_csplit<<<GB, 1024, 0, stream>>>(esrc, edst, ccur, tmp);
  k_fsort<<<NB, 1024, 0, stream>>>(tmp, cbase, chist, rowptr, psrc);

  // gbuf zero AFTER tmp is dead (aliases the same region)
  hipMemsetAsync(gbuf, 0, (size_t)GG * HD * 4, stream);

  // three fused conv layers
  k_conv<0><<<gConv, B, 0, stream>>>(rowptr, psrc, x,
                                     cW[0][0], cW[0][1], cW[0][2], cW[0][3],
                                     nullptr, nullptr, cW[0][4], cW[0][5],
                                     Wc0l, bc0l, Wc0r, bc0r, nullptr, nullptr,
                                     xlhB, xrB, nullptr, nullptr);
  k_conv<1><<<gConv, B, 0, stream>>>(rowptr, psrc, nullptr,
                                     nullptr, nullptr, nullptr, nullptr,
                                     xlhB, xrB, cW[1][4], cW[1][5],
                                     Wc1l, bc1l, Wc1r, bc1r, nullptr, nullptr,
                                     xlhA, xrA, nullptr, nullptr);
  k_conv<2><<<gConv, B, 0, stream>>>(rowptr, psrc, nullptr,
                                     nullptr, nullptr, nullptr, nullptr,
                                     xlhA, xrA, cW[2][4], cW[2][5],
                                     nullptr, nullptr, nullptr, nullptr,
                                     lW[2][0], lW[2][1],
                                     nullptr, nullptr, gbuf, batch);

  k_mlp<<<gMlp, B, 0, stream>>>(gbuf, oW[0], ob[0], oW[1], ob[1], oW[2], ob[2],
                                (float*)d_out);
}

// Round 12
// 208.222 us; speedup vs baseline: 1.0506x; 1.0506x over previous
//
#include <hip/hip_runtime.h>
#include <hip/hip_fp16.h>

#define HD 16

static constexpr int NN = 100000;   // nodes
static constexpr int EE = 3200000;  // edges (before self-loops)
static constexpr int GG = 1000;     // graphs
static constexpr int ET = EE + NN;  // edges incl. self-loops
static constexpr float NEG = 0.2f;  // leaky_relu slope
static constexpr float LOG2E = 1.44269504f;

static constexpr int BSH = 8;                       // 256 nodes per bucket
static constexpr int NB = (NN + 255) >> BSH;        // 391 buckets
static constexpr int EPB = 8192;                    // edges per block (bucket passes)
static constexpr int GB = (ET + EPB - 1) / EPB;     // 403 blocks
static constexpr int ITER = EPB / 1024;             // 8 edges per thread

__device__ __forceinline__ int imin(int a, int b) { return a < b ? a : b; }

// unpack 2 fp16 from a dword
__device__ __forceinline__ float2 up2(unsigned u) {
  __half2 h = *reinterpret_cast<__half2*>(&u);
  return __half22float2(h);
}

// ---- DPP helpers ----
template <int N>
__device__ __forceinline__ float row_ror_add(float v) {
  int m = __builtin_amdgcn_update_dpp(0, __float_as_int(v), 0x120 + N, 0xF, 0xF, true);
  return v + __int_as_float(m);
}
// pair sum (lanes differing in bit0) via quad_perm [1,0,3,2]
__device__ __forceinline__ float pair_sum(float v) {
  int m = __builtin_amdgcn_update_dpp(0, __float_as_int(v), 0xB1, 0xF, 0xF, true);
  return v + __int_as_float(m);
}
// reduce over the 16 edge-slots of a 32-lane half (parity-preserving rotations
// within each 16-row, then cross-row); every lane ends with its octet's total
__device__ __forceinline__ float slot_red(float v) {
  v = row_ror_add<2>(v);
  v = row_ror_add<4>(v);
  v = row_ror_add<8>(v);
  v += __shfl_xor(v, 16, 64);
  return v;
}

// ---------- pass A: coarse histogram (LDS-aggregated) ----------
__global__ void k_chist(const int* __restrict__ edst, int* __restrict__ chist) {
  __shared__ int sh[NB];
  int t = threadIdx.x;
  for (int i = t; i < NB; i += 1024) sh[i] = 0;
  __syncthreads();
  int b0 = blockIdx.x * EPB;
#pragma unroll
  for (int i = 0; i < ITER; ++i) {
    int e = b0 + t + i * 1024;
    if (e < ET) {
      int d = (e < EE) ? edst[e] : e - EE;  // self-loop block appended at end
      atomicAdd(&sh[d >> BSH], 1);
    }
  }
  __syncthreads();
  for (int i = t; i < NB; i += 1024)
    if (sh[i]) atomicAdd(&chist[i], sh[i]);
}

// ---------- scan coarse histogram -> bucket bases ----------
__global__ void k_cscan(const int* __restrict__ chist, int* __restrict__ cbase,
                        int* __restrict__ ccur, int* __restrict__ rowptr) {
  __shared__ int sh[512];
  int t = threadIdx.x;
  sh[t] = (t < NB) ? chist[t] : 0;
  __syncthreads();
  for (int off = 1; off < 512; off <<= 1) {
    int v = sh[t];
    int a = (t >= off) ? sh[t - off] : 0;
    __syncthreads();
    sh[t] = v + a;
    __syncthreads();
  }
  if (t < NB) {
    int b = (t == 0) ? 0 : sh[t - 1];
    cbase[t] = b;
    ccur[t] = b;
  }
  if (t == 0) rowptr[NN] = ET;
}

// ---------- pass B: scatter packed records into coarse bucket regions ----------
// record = (dst & 255) << 17 | src   (src < 2^17, local dst < 2^8 -> 25 bits)
__global__ void k_csplit(const int* __restrict__ esrc, const int* __restrict__ edst,
                         int* __restrict__ ccur, unsigned* __restrict__ tmp) {
  __shared__ int hist[NB];
  __shared__ int base[NB];
  int t = threadIdx.x;
  for (int i = t; i < NB; i += 1024) hist[i] = 0;
  __syncthreads();
  int b0 = blockIdx.x * EPB;
  int sl[ITER], dl[ITER];
#pragma unroll
  for (int i = 0; i < ITER; ++i) {
    int e = b0 + t + i * 1024;
    int s = -1, d = 0;
    if (e < ET) {
      if (e < EE) { s = esrc[e]; d = edst[e]; } else { s = e - EE; d = s; }
      atomicAdd(&hist[d >> BSH], 1);
    }
    sl[i] = s; dl[i] = d;
  }
  __syncthreads();
  for (int i = t; i < NB; i += 1024) {
    int c = hist[i];
    base[i] = c ? atomicAdd(&ccur[i], c) : 0;  // one reservation per bucket per block
    hist[i] = 0;                               // reuse as running counter
  }
  __syncthreads();
#pragma unroll
  for (int i = 0; i < ITER; ++i) {
    int s = sl[i];
    if (s >= 0) {
      int d = dl[i], bb = d >> BSH;
      int slot = base[bb] + atomicAdd(&hist[bb], 1);
      tmp[slot] = ((unsigned)(d & 255) << 17) | (unsigned)s;
    }
  }
}

// ---------- pass C: per-bucket fine counting sort -> rowptr + psrc ----------
__global__ void k_fsort(const unsigned* __restrict__ tmp, const int* __restrict__ cbase,
                        const int* __restrict__ chist, int* __restrict__ rowptr,
                        int* __restrict__ psrc) {
  __shared__ int fh[256];
  __shared__ int fs[256];
  int b = blockIdx.x, t = threadIdx.x;
  if (t < 256) fh[t] = 0;
  __syncthreads();
  int beg = cbase[b], cnt = chist[b];
  for (int i = t; i < cnt; i += 1024)
    atomicAdd(&fh[tmp[beg + i] >> 17], 1);
  __syncthreads();
  if (t < 256) fs[t] = fh[t];
  __syncthreads();
  for (int off = 1; off < 256; off <<= 1) {
    int v = 0, a = 0;
    if (t < 256) { v = fs[t]; if (t >= off) a = fs[t - off]; }
    __syncthreads();
    if (t < 256) fs[t] = v + a;
    __syncthreads();
  }
  if (t < 256) {
    int ex = fs[t] - fh[t];  // exclusive within bucket
    fs[t] = ex;              // becomes the running placement counter
    int node = (b << BSH) + t;
    if (node < NN) rowptr[node] = beg + ex;
  }
  __syncthreads();
  for (int i = t; i < cnt; i += 1024) {
    unsigned v = tmp[beg + i];
    int ld = v >> 17;
    psrc[beg + atomicAdd(&fs[ld], 1)] = (int)(v & 0x1FFFFu);
  }
}

// ---------- fold inter-layer linear into next projections: Wc = W@P, bc = b@P + bp ----------
__global__ void k_comb(const float* __restrict__ W0, const float* __restrict__ b0,
                       const float* __restrict__ Wl1, const float* __restrict__ bl1,
                       const float* __restrict__ Wr1, const float* __restrict__ br1,
                       const float* __restrict__ W1, const float* __restrict__ b1,
                       const float* __restrict__ Wl2, const float* __restrict__ bl2,
                       const float* __restrict__ Wr2, const float* __restrict__ br2,
                       float* __restrict__ Wc0l, float* __restrict__ bc0l,
                       float* __restrict__ Wc0r, float* __restrict__ bc0r,
                       float* __restrict__ Wc1l, float* __restrict__ bc1l,
                       float* __restrict__ Wc1r, float* __restrict__ bc1r) {
  const float *W, *b, *P, *bp;
  float *Wo, *bo;
  switch (blockIdx.x) {
    case 0:  W = W0; b = b0; P = Wl1; bp = bl1; Wo = Wc0l; bo = bc0l; break;
    case 1:  W = W0; b = b0; P = Wr1; bp = br1; Wo = Wc0r; bo = bc0r; break;
    case 2:  W = W1; b = b1; P = Wl2; bp = bl2; Wo = Wc1l; bo = bc1l; break;
    default: W = W1; b = b1; P = Wr2; bp = br2; Wo = Wc1r; bo = bc1r; break;
  }
  int t = threadIdx.x;  // 256
  int c = t >> 4, k = t & 15;
  float s = 0.f;
#pragma unroll
  for (int i = 0; i < 16; ++i) s = fmaf(W[c * 16 + i], P[i * 16 + k], s);
  Wo[t] = s;
  if (t < 16) {
    float sb = bp[t];
#pragma unroll
    for (int i = 0; i < 16; ++i) sb = fmaf(b[i], P[i * 16 + t], sb);
    bo[t] = sb;
  }
}

// ---------- fused conv layer: TWO nodes per wave, PAIR layout, LDS constants ----------
// All layer constants (att*log2e, cbias, folded W's, biases, MODE-0 rank-1
// vectors) staged ONCE PER BLOCK into LDS -> prologue/epilogue become TA-free
// (DS reads); per-wave vector-memory instrs drop ~34 -> ~12. Loop = round-11
// pair layout (16 edge-slots x 2 octets per half, 16B gathers, value prefetch).
// MODE 0 = first (xl/xr rank-1 from x), 1 = mid, 2 = last (pool).
// NOTE: grid is exact (NN*32 threads, NN even) -> every lane owns a valid node.
template <int MODE>
__global__ void k_conv(const int* __restrict__ rowptr, const int* __restrict__ psrc,
                       const float* __restrict__ x,
                       const float* __restrict__ Wl0, const float* __restrict__ bl0,
                       const float* __restrict__ Wr0, const float* __restrict__ br0,
                       const __half* __restrict__ xlh, const float* __restrict__ xr,
                       const float* __restrict__ att, const float* __restrict__ cbias,
                       const float* __restrict__ Wcl, const float* __restrict__ bcl,
                       const float* __restrict__ Wcr, const float* __restrict__ bcr,
                       const float* __restrict__ Wlast, const float* __restrict__ blast,
                       __half* __restrict__ oxlh, float* __restrict__ oxr,
                       float* __restrict__ gpool, const int* __restrict__ batch) {
  __shared__ __align__(16) float s_att[16], s_cb[16], s_b1[16], s_b2[16];
  __shared__ __align__(16) float s_W1[256], s_W2[256];
  __shared__ __align__(16) float s_wl[16], s_bl[16], s_wr[16], s_br[16];
  __shared__ float hsh[4][2][16];
  int t = threadIdx.x;
  // ---- block-cooperative constant staging (few coalesced loads per block) ----
  if constexpr (MODE == 2) {
    if (t < 256) s_W1[t] = Wlast[t];
    if (t >= 256 - 48 && t < 256 - 32) {
      int i = t - (256 - 48);
      s_att[i] = att[i] * LOG2E; s_cb[i] = cbias[i]; s_b1[i] = blast[i];
    }
  } else {
    s_W1[t] = Wcl[t];
    if (t < 16) {
      s_att[t] = att[t] * LOG2E; s_cb[t] = cbias[t];
      s_b1[t] = bcl[t]; s_b2[t] = bcr[t];
    }
  }
  if constexpr (MODE != 2) {
    // second matrix staged by the upper half... all 256 threads already used;
    // reuse them (separate if to keep single pass):
    s_W2[t] = Wcr[t];
  }
  if constexpr (MODE == 0) {
    if (t >= 32 && t < 48) {
      int i = t - 32;
      s_wl[i] = Wl0[i]; s_bl[i] = bl0[i]; s_wr[i] = Wr0[i]; s_br[i] = br0[i];
    }
  }
  __syncthreads();

  int gt = blockIdx.x * blockDim.x + t;
  int wave = gt >> 6;
  int lane = t & 63;
  int hf = lane >> 5;        // which node of the pair
  int lane5 = lane & 31;
  int slot = lane5 >> 1;     // edge slot 0..15
  int o = lane & 1;          // feature octet (features 8o..8o+7)
  int n = wave * 2 + hf;     // always < NN (exact grid)
  int f0 = o * 8;
  // per-lane octets from LDS (no TA)
  float4 attA = *reinterpret_cast<const float4*>(&s_att[f0]);
  float4 attB = *reinterpret_cast<const float4*>(&s_att[f0 + 4]);
  float4 xrA, xrB, wlA, wlB, blA, blB;
  if constexpr (MODE == 0) {
    wlA = *reinterpret_cast<const float4*>(&s_wl[f0]);
    wlB = *reinterpret_cast<const float4*>(&s_wl[f0 + 4]);
    blA = *reinterpret_cast<const float4*>(&s_bl[f0]);
    blB = *reinterpret_cast<const float4*>(&s_bl[f0 + 4]);
    float4 wrA = *reinterpret_cast<const float4*>(&s_wr[f0]);
    float4 wrB = *reinterpret_cast<const float4*>(&s_wr[f0 + 4]);
    float4 brA = *reinterpret_cast<const float4*>(&s_br[f0]);
    float4 brB = *reinterpret_cast<const float4*>(&s_br[f0 + 4]);
    float xn = x[n];
    xrA.x = fmaf(xn, wrA.x, brA.x); xrA.y = fmaf(xn, wrA.y, brA.y);
    xrA.z = fmaf(xn, wrA.z, brA.z); xrA.w = fmaf(xn, wrA.w, brA.w);
    xrB.x = fmaf(xn, wrB.x, brB.x); xrB.y = fmaf(xn, wrB.y, brB.y);
    xrB.z = fmaf(xn, wrB.z, brB.z); xrB.w = fmaf(xn, wrB.w, brB.w);
  } else {
    xrA = *reinterpret_cast<const float4*>(xr + (size_t)n * HD + f0);
    xrB = *reinterpret_cast<const float4*>(xr + (size_t)n * HD + f0 + 4);
  }
  int beg = rowptr[n], end = rowptr[n + 1];
  int e1 = end - 1;
  int p = beg + slot;
  // pipeline prologue: iter-0 value + iter-1 index
  int i0 = psrc[imin(p, e1)];
  uint4 cv;           // MODE!=0: 8 fp16 features of current edge
  float cx;           // MODE==0: raw x of current edge's src
  if constexpr (MODE == 0) {
    cx = x[i0];
  } else {
    cv = *reinterpret_cast<const uint4*>(
        (const char*)xlh + (size_t)i0 * 32 + (size_t)o * 16);
  }
  int t0 = psrc[imin(p + 16, e1)];
  float l = 0.f;
  float a0 = 0.f, a1 = 0.f, a2 = 0.f, a3 = 0.f;
  float a4 = 0.f, a5 = 0.f, a6 = 0.f, a7 = 0.f;
  for (; p < end; p += 16) {
    // issue next iteration's value gather + index prefetch
    uint4 nv;
    float nx;
    if constexpr (MODE == 0) {
      nx = x[t0];
    } else {
      nv = *reinterpret_cast<const uint4*>(
          (const char*)xlh + (size_t)t0 * 32 + (size_t)o * 16);
    }
    int t1 = psrc[imin(p + 32, e1)];
    // materialize current edge's 8 features
    float x0, x1, x2, x3, x4, x5, x6, x7;
    if constexpr (MODE == 0) {
      x0 = fmaf(cx, wlA.x, blA.x); x1 = fmaf(cx, wlA.y, blA.y);
      x2 = fmaf(cx, wlA.z, blA.z); x3 = fmaf(cx, wlA.w, blA.w);
      x4 = fmaf(cx, wlB.x, blB.x); x5 = fmaf(cx, wlB.y, blB.y);
      x6 = fmaf(cx, wlB.z, blB.z); x7 = fmaf(cx, wlB.w, blB.w);
    } else {
      float2 f01 = up2(cv.x), f23 = up2(cv.y), f45 = up2(cv.z), f67 = up2(cv.w);
      x0 = f01.x; x1 = f01.y; x2 = f23.x; x3 = f23.y;
      x4 = f45.x; x5 = f45.y; x6 = f67.x; x7 = f67.y;
    }
    // 8-feature score partial
    float u, sp = 0.f;
    u = x0 + xrA.x; u = fmaxf(u, NEG * u); sp = fmaf(u, attA.x, sp);
    u = x1 + xrA.y; u = fmaxf(u, NEG * u); sp = fmaf(u, attA.y, sp);
    u = x2 + xrA.z; u = fmaxf(u, NEG * u); sp = fmaf(u, attA.z, sp);
    u = x3 + xrA.w; u = fmaxf(u, NEG * u); sp = fmaf(u, attA.w, sp);
    u = x4 + xrB.x; u = fmaxf(u, NEG * u); sp = fmaf(u, attB.x, sp);
    u = x5 + xrB.y; u = fmaxf(u, NEG * u); sp = fmaf(u, attB.y, sp);
    u = x6 + xrB.z; u = fmaxf(u, NEG * u); sp = fmaf(u, attB.z, sp);
    u = x7 + xrB.w; u = fmaxf(u, NEG * u); sp = fmaf(u, attB.w, sp);
    float sc = pair_sum(sp);          // full 16-feature score (both octets)
    float pe = __builtin_amdgcn_exp2f(sc);
    l += pe;
    a0 = fmaf(pe, x0, a0); a1 = fmaf(pe, x1, a1);
    a2 = fmaf(pe, x2, a2); a3 = fmaf(pe, x3, a3);
    a4 = fmaf(pe, x4, a4); a5 = fmaf(pe, x5, a5);
    a6 = fmaf(pe, x6, a6); a7 = fmaf(pe, x7, a7);
    // rotate pipeline
    if constexpr (MODE == 0) cx = nx; else cv = nv;
    t0 = t1;
  }
  // reduce over the 16 slots of the half (lanes that never looped contribute 0)
  l = slot_red(l);
  a0 = slot_red(a0); a1 = slot_red(a1); a2 = slot_red(a2); a3 = slot_red(a3);
  a4 = slot_red(a4); a5 = slot_red(a5); a6 = slot_red(a6); a7 = slot_red(a7);
  float rl = __builtin_amdgcn_rcpf(l);
  float4 cbA = *reinterpret_cast<const float4*>(&s_cb[f0]);
  float4 cbB = *reinterpret_cast<const float4*>(&s_cb[f0 + 4]);
  float h0 = fmaxf(fmaf(a0, rl, cbA.x), 0.f);
  float h1 = fmaxf(fmaf(a1, rl, cbA.y), 0.f);
  float h2 = fmaxf(fmaf(a2, rl, cbA.z), 0.f);
  float h3 = fmaxf(fmaf(a3, rl, cbA.w), 0.f);
  float h4 = fmaxf(fmaf(a4, rl, cbB.x), 0.f);
  float h5 = fmaxf(fmaf(a5, rl, cbB.y), 0.f);
  float h6 = fmaxf(fmaf(a6, rl, cbB.z), 0.f);
  float h7 = fmaxf(fmaf(a7, rl, cbB.w), 0.f);
  // publish h to LDS: slot-0 lanes (lane5 = 0,1) hold the full sums
  int w = t >> 6;
  if (lane5 < 2) {
    *reinterpret_cast<float4*>(&hsh[w][hf][f0]) = make_float4(h0, h1, h2, h3);
    *reinterpret_cast<float4*>(&hsh[w][hf][f0 + 4]) = make_float4(h4, h5, h6, h7);
  }
  int sub = lane5 >> 4;      // 0 or 1
  int k = lane5 & 15;
  const float* hrow = hsh[w][hf];
  if constexpr (MODE == 2) {
    // o = h @ Wlast (+ blast): sub-split rows, xor-16 combine (W from LDS)
    float ov = 0.f;
#pragma unroll
    for (int i = 0; i < 8; ++i) {
      int c = 8 * sub + i;
      ov = fmaf(hrow[c], s_W1[c * HD + k], ov);
    }
    ov += __shfl_xor(ov, 16, 64);
    if (sub == 0) atomicAdd(gpool + (size_t)batch[n] * HD + k, ov + s_b1[k]);
  } else {
    // sub0 computes full xl2 (Wcl), sub1 computes full xr2 (Wcr) in parallel
    const float* Wsel = sub ? s_W2 : s_W1;
    float ov = 0.f;
#pragma unroll
    for (int c = 0; c < 16; ++c) ov = fmaf(hrow[c], Wsel[c * HD + k], ov);
    if (sub == 0) oxlh[(size_t)n * HD + k] = __float2half(ov + s_b1[k]);
    else          oxr[(size_t)n * HD + k] = ov + s_b2[k];
  }
}

// ---------- graph-level MLP head: [G,16] -> [G,1] ----------
__global__ void k_mlp(const float* __restrict__ g,
                      const float* __restrict__ W0, const float* __restrict__ b0,
                      const float* __restrict__ W1, const float* __restrict__ b1,
                      const float* __restrict__ W2, const float* __restrict__ b2,
                      float* __restrict__ out) {
  int gi = blockIdx.x * blockDim.x + threadIdx.x;
  if (gi >= GG) return;
  float v[HD], a[HD];
  const float4* g4 = reinterpret_cast<const float4*>(g + (size_t)gi * HD);
#pragma unroll
  for (int i = 0; i < 4; ++i) {
    float4 tv = g4[i];
    v[4 * i] = tv.x; v[4 * i + 1] = tv.y; v[4 * i + 2] = tv.z; v[4 * i + 3] = tv.w;
  }
#pragma unroll
  for (int j = 0; j < HD; ++j) {
    float s = b0[j];
#pragma unroll
    for (int kk = 0; kk < HD; ++kk) s = fmaf(v[kk], W0[kk * HD + j], s);
    a[j] = s > 0.f ? s : 0.f;
  }
#pragma unroll
  for (int j = 0; j < HD; ++j) {
    float s = b1[j];
#pragma unroll
    for (int kk = 0; kk < HD; ++kk) s = fmaf(a[kk], W1[kk * HD + j], s);
    v[j] = s > 0.f ? s : 0.f;
  }
  float s = b2[0];
#pragma unroll
  for (int kk = 0; kk < HD; ++kk) s = fmaf(v[kk], W2[kk], s);
  out[gi] = s;
}

extern "C" void kernel_launch(void* const* d_in, const int* in_sizes, int n_in,
                              void* d_out, int out_size, void* d_ws, size_t ws_size,
                              hipStream_t stream) {
  const float* x = (const float*)d_in[0];
  const int* ei = (const int*)d_in[1];  // [2, EE] int32
  const int* batch = (const int*)d_in[2];
  const int* esrc = ei;
  const int* edst = ei + EE;

  const float* cW[3][6];  // Wl bl Wr br att bias
  const float* lW[3][2];  // W b
  int i = 3;
  for (int l = 0; l < 3; ++l) {
    for (int j = 0; j < 6; ++j) cW[l][j] = (const float*)d_in[i++];
    lW[l][0] = (const float*)d_in[i++];
    lW[l][1] = (const float*)d_in[i++];
  }
  const float *oW[3], *ob[3];
  for (int j = 0; j < 3; ++j) {
    oW[j] = (const float*)d_in[i++];
    ob[j] = (const float*)d_in[i++];
  }

  // workspace carve-up (~33 MB), 256B-aligned slices
  char* ws = (char*)d_ws;
  size_t off = 0;
  auto alloc = [&](size_t bytes) {
    void* p = ws + off;
    off = (off + bytes + 255) & ~(size_t)255;
    return p;
  };
  int* psrc = (int*)alloc((size_t)ET * 4);
  int* rowptr = (int*)alloc((size_t)(NN + 1) * 4);
  int* chist = (int*)alloc((size_t)NB * 4);
  int* cbase = (int*)alloc((size_t)NB * 4);
  int* ccur = (int*)alloc((size_t)NB * 4);
  float* Wc0l = (float*)alloc(256 * 4);
  float* Wc0r = (float*)alloc(256 * 4);
  float* Wc1l = (float*)alloc(256 * 4);
  float* Wc1r = (float*)alloc(256 * 4);
  float* bc0l = (float*)alloc(16 * 4);
  float* bc0r = (float*)alloc(16 * 4);
  float* bc1l = (float*)alloc(16 * 4);
  float* bc1r = (float*)alloc(16 * 4);
  // union region: tmp (ET*4 = 13.2MB) dead after k_fsort; feature buffers
  // (2x half 3.2MB + 2x f32 6.4MB + gbuf 64KB = 19.3MB) written only after.
  size_t NNHD = (size_t)NN * HD;
  size_t featBytes = NNHD * 12 + (size_t)GG * HD * 4;
  size_t uniBytes = (size_t)ET * 4 > featBytes ? (size_t)ET * 4 : featBytes;
  char* uni = (char*)alloc(uniBytes);
  unsigned* tmp = (unsigned*)uni;
  __half* xlhB = (__half*)uni;
  float* xrB = (float*)(uni + NNHD * 2);
  __half* xlhA = (__half*)(uni + NNHD * 6);
  float* xrA = (float*)(uni + NNHD * 8);
  float* gbuf = (float*)(uni + NNHD * 12);

  const int B = 256;
  const int gConv = (NN * 32 + B - 1) / B;  // HALF-wave per node (2 nodes/wave)
  const int gMlp = (GG + B - 1) / B;

  hipMemsetAsync(chist, 0, (size_t)NB * 4, stream);

  // tiny weight-fold kernel (independent of CSR; overlaps it)
  k_comb<<<4, 256, 0, stream>>>(lW[0][0], lW[0][1],
                                cW[1][0], cW[1][1], cW[1][2], cW[1][3],
                                lW[1][0], lW[1][1],
                                cW[2][0], cW[2][1], cW[2][2], cW[2][3],
                                Wc0l, bc0l, Wc0r, bc0r, Wc1l, bc1l, Wc1r, bc1r);

  // CSR build: all per-edge atomics in LDS
  k_chist<<<GB, 1024, 0, stream>>>(edst, chist);
  k_cscan<<<1, 512, 0, stream>>>(chist, cbase, ccur, rowptr);
  k_csplit<<<GB, 1024, 0, stream>>>(esrc, edst, ccur, tmp);
  k_fsort<<<NB, 1024, 0, stream>>>(tmp, cbase, chist, rowptr, psrc);

  // gbuf zero AFTER tmp is dead (aliases the same region)
  hipMemsetAsync(gbuf, 0, (size_t)GG * HD * 4, stream);

  // three fused conv layers
  k_conv<0><<<gConv, B, 0, stream>>>(rowptr, psrc, x,
                                     cW[0][0], cW[0][1], cW[0][2], cW[0][3],
                                     nullptr, nullptr, cW[0][4], cW[0][5],
                                     Wc0l, bc0l, Wc0r, bc0r, nullptr, nullptr,
                                     xlhB, xrB, nullptr, nullptr);
  k_conv<1><<<gConv, B, 0, stream>>>(rowptr, psrc, nullptr,
                                     nullptr, nullptr, nullptr, nullptr,
                                     xlhB, xrB, cW[1][4], cW[1][5],
                                     Wc1l, bc1l, Wc1r, bc1r, nullptr, nullptr,
                                     xlhA, xrA, nullptr, nullptr);
  k_conv<2><<<gConv, B, 0, stream>>>(rowptr, psrc, nullptr,
                                     nullptr, nullptr, nullptr, nullptr,
                                     xlhA, xrA, cW[2][4], cW[2][5],
                                     nullptr, nullptr, nullptr, nullptr,
                                     lW[2][0], lW[2][1],
                                     nullptr, nullptr, gbuf, batch);

  k_mlp<<<gMlp, B, 0, stream>>>(gbuf, oW[0], ob[0], oW[1], ob[1], oW[2], ob[2],
                                (float*)d_out);
}